// Round 1
// baseline (1436.110 us; speedup 1.0000x reference)
//
#include <hip/hip_runtime.h>
#include <hip/hip_bf16.h>

// Problem constants (from reference)
#define NN 16384
#define EE 65536
#define DD 64
#define HH 128
#define LL 3
#define GG 512
#define OUTD 128
#define NEG 0.01f   // jax.nn.leaky_relu default slope

typedef __attribute__((ext_vector_type(8))) short short8;
typedef __attribute__((ext_vector_type(4))) float f32x4;

__device__ __forceinline__ float leaky(float x){ return x > 0.f ? x : NEG * x; }
__device__ __forceinline__ unsigned short f2bf(float f){
  union { float f; unsigned int u; } v; v.f = f;
  unsigned int r = v.u + 0x7fffu + ((v.u >> 16) & 1u);   // RNE
  return (unsigned short)(r >> 16);
}

// ---------------- CSR build ----------------
__global__ void k_deg(const int* ei, int* deg){
  int e = blockIdx.x*256 + threadIdx.x;
  if (e < EE) atomicAdd(&deg[ei[EE + e]], 1);   // row 1 of edge_index = dst
}
__global__ void k_cnt(const int* batch, int* cnt){
  int n = blockIdx.x*256 + threadIdx.x;
  if (n < NN) atomicAdd(&cnt[batch[n]], 1);
}
__global__ void k_scan(const int* deg, int* row_ptr){
  __shared__ int part[256];
  int t = threadIdx.x;
  int base = t*64; int s = 0;
  for (int i=0;i<64;++i) s += deg[base+i];
  part[t] = s; __syncthreads();
  for (int off=1; off<256; off<<=1){
    int v = (t>=off)?part[t-off]:0; __syncthreads();
    part[t] += v; __syncthreads();
  }
  int run = (t==0)?0:part[t-1];
  if (t==0) row_ptr[0] = 0;
  for (int i=0;i<64;++i){ run += deg[base+i]; row_ptr[base+i+1] = run; }
}
__global__ void k_fill(const int* ei, const int* row_ptr, int* cursor, int* edge_id){
  int e = blockIdx.x*256 + threadIdx.x;
  if (e < EE){
    int d = ei[EE + e];
    int pos = row_ptr[d] + atomicAdd(&cursor[d], 1);
    edge_id[pos] = e;
  }
}

// ---------------- LayerNorm + leaky ----------------
__global__ void k_ln(const float* x, const float* scale, const float* bias, float* h, int l){
  int t = threadIdx.x, lane = t & 63, nl = t >> 6;
  int n = blockIdx.x*4 + nl;
  float v = x[(size_t)n*DD + lane];
  float s = v;
  for (int m=1;m<64;m<<=1) s += __shfl_xor(s, m, 64);
  float mu = s * (1.0f/64.0f);
  float dv = v - mu;
  float q = dv*dv;
  for (int m=1;m<64;m<<=1) q += __shfl_xor(q, m, 64);
  float var = q * (1.0f/64.0f);
  float w = dv * rsqrtf(var + 1e-5f) * scale[l*DD + lane] + bias[l*DD + lane];
  h[(size_t)n*DD + lane] = leaky(w);
}

// ---------------- edge MLP: u = leaky(ea @ W1[l] + b1[l])  [E,128] ----------------
__global__ void k_edge_mlp(const float* ea, const float* W1, const float* b1, float* u, int l){
  __shared__ float eat[32][64];
  int t = threadIdx.x;
  int e0 = blockIdx.x * 32;
  for (int idx = t; idx < 32*64; idx += 256)
    eat[idx>>6][idx&63] = ea[(size_t)(e0 + (idx>>6))*DD + (idx&63)];
  int j = t & 127, half = t >> 7;
  float w1c[64];
  #pragma unroll
  for (int d=0; d<64; ++d) w1c[d] = W1[(size_t)(l*DD + d)*HH + j];
  float bj = b1[l*HH + j];
  __syncthreads();
  for (int i=0;i<16;++i){
    int el = half + 2*i;
    float acc = bj;
    #pragma unroll
    for (int d=0; d<64; ++d) acc += eat[el][d] * w1c[d];
    u[(size_t)(e0+el)*HH + j] = leaky(acc);
  }
}

// ---------------- W2[l] -> bf16 transposed [f][kd]  (kd = k*64+d, contiguous K) ----------------
__global__ void k_w2t(const float* W2, unsigned short* W2T, int l){
  int idx = blockIdx.x*256 + threadIdx.x;    // < 64*8192
  int f = idx >> 13, kd = idx & 8191;
  W2T[idx] = f2bf(W2[(size_t)l*HH*DD*DD + (size_t)kd*DD + f]);
}

// ---------------- S-build: S[n_local, kd] = sum_{e->n} u[e,k]*h[src_e,d]  (bf16 out) ----------
__global__ void k_sbuild(const float* u, const float* h, const int* ei,
                         const int* row_ptr, const int* edge_id,
                         unsigned short* S, float* Hs, int chunk_base){
  __shared__ float eu[32][HH];
  __shared__ float eh[32][DD];
  int t = threadIdx.x;
  int n = chunk_base + blockIdx.x;
  int r0 = row_ptr[n], r1 = row_ptr[n+1];
  float acc[32];
  #pragma unroll
  for (int i=0;i<32;++i) acc[i] = 0.f;
  float hs = 0.f;
  int d = t & 63, k0 = t >> 6;    // thread owns kd = t + 256*i -> d=t&63, k=k0+4i
  for (int rb = r0; rb < r1; rb += 32){
    int nb = min(32, r1 - rb);
    for (int idx = t; idx < nb*HH; idx += 256){
      int el = idx >> 7, c = idx & 127;
      int e = edge_id[rb + el];
      eu[el][c] = u[(size_t)e*HH + c];
    }
    for (int idx = t; idx < nb*DD; idx += 256){
      int el = idx >> 6, c = idx & 63;
      int e = edge_id[rb + el];
      int s = ei[e];               // row 0 of edge_index = src
      eh[el][c] = h[(size_t)s*DD + c];
    }
    __syncthreads();
    for (int el = 0; el < nb; ++el){
      float hv = eh[el][d];
      #pragma unroll
      for (int i=0;i<32;++i) acc[i] += eu[el][k0 + 4*i] * hv;
    }
    if (t < 64){
      for (int el = 0; el < nb; ++el) hs += eh[el][t];
    }
    __syncthreads();
  }
  size_t sb = (size_t)blockIdx.x * 8192;
  #pragma unroll
  for (int i=0;i<32;++i) S[sb + t + 256*i] = f2bf(acc[i]);
  if (t < 64) Hs[(size_t)n*DD + t] = hs;
}

// ---------------- GEMM: num[chunk rows, 64] += S[4096,8192] @ W2T^T, bf16 MFMA, split-K -------
__global__ void k_gemm(const unsigned short* S, const unsigned short* W2T,
                       float* num, int chunk_base){
  __shared__ __align__(16) unsigned short a_lds[128][72];  // +8 pad: conflict-free b128
  __shared__ __align__(16) unsigned short b_lds[64][72];
  int t = threadIdx.x;
  int wave = t >> 6, lane = t & 63;
  int rowblk = blockIdx.x, kseg = blockIdx.y;  // 32 x 8
  int lr = lane & 15, lq = lane >> 4;
  f32x4 acc[2][4];
  for (int a=0;a<2;++a) for (int b=0;b<4;++b) acc[a][b] = (f32x4){0.f,0.f,0.f,0.f};
  int m0 = wave * 32;
  for (int it = 0; it < 16; ++it){            // 16 x 64 = 1024 kd per kseg
    int kbase = kseg*1024 + it*64;
    #pragma unroll
    for (int ii=0; ii<4; ++ii){               // stage A: 128 rows x 64 kd
      int idx = t + 256*ii;
      int r = idx >> 3, c8 = (idx & 7) << 3;
      float4 v = *(const float4*)(S + (size_t)(rowblk*128 + r)*8192 + kbase + c8);
      *(float4*)&a_lds[r][c8] = v;
    }
    #pragma unroll
    for (int ii=0; ii<2; ++ii){               // stage B: 64 f x 64 kd (transposed W2)
      int idx = t + 256*ii;
      int r = idx >> 3, c8 = (idx & 7) << 3;
      float4 v = *(const float4*)(W2T + (size_t)r*8192 + kbase + c8);
      *(float4*)&b_lds[r][c8] = v;
    }
    __syncthreads();
    #pragma unroll
    for (int kk=0; kk<64; kk+=32){
      short8 a0 = *(const short8*)&a_lds[m0 + lr][kk + lq*8];
      short8 a1 = *(const short8*)&a_lds[m0 + 16 + lr][kk + lq*8];
      #pragma unroll
      for (int ft=0; ft<4; ++ft){
        short8 b = *(const short8*)&b_lds[ft*16 + lr][kk + lq*8];
        acc[0][ft] = __builtin_amdgcn_mfma_f32_16x16x32_bf16(a0, b, acc[0][ft], 0, 0, 0);
        acc[1][ft] = __builtin_amdgcn_mfma_f32_16x16x32_bf16(a1, b, acc[1][ft], 0, 0, 0);
      }
    }
    __syncthreads();
  }
  // C/D layout: col = lane&15, row = (lane>>4)*4 + reg   [m89/m91 verified]
  #pragma unroll
  for (int rt=0; rt<2; ++rt)
    #pragma unroll
    for (int ft=0; ft<4; ++ft)
      #pragma unroll
      for (int r=0; r<4; ++r){
        int m = m0 + rt*16 + lq*4 + r;
        int f = ft*16 + lr;
        int n = chunk_base + rowblk*128 + m;
        atomicAdd(&num[(size_t)n*DD + f], acc[rt][ft][r]);
      }
}

// ---------------- node update: x += num/deg + h@root + Hs@b2 + conv_b ----------------
__global__ void k_update(float* x, const float* num, const float* h, const float* Hs,
                         const int* deg, const float* root, const float* b2,
                         const float* conv_b, int l){
  __shared__ float rl[64][64];
  __shared__ float b2l[64][64];
  __shared__ float hrow[4][64];
  __shared__ float hsrow[4][64];
  int t = threadIdx.x;
  int f = t & 63, nl = t >> 6;
  for (int idx=t; idx<4096; idx+=256){
    rl[idx>>6][idx&63]  = root[(size_t)l*4096 + idx];
    b2l[idx>>6][idx&63] = b2[(size_t)l*4096 + idx];
  }
  int n = blockIdx.x*4 + nl;
  hrow[nl][f]  = h[(size_t)n*DD + f];
  hsrow[nl][f] = Hs[(size_t)n*DD + f];
  __syncthreads();
  float dg = (float)deg[n]; if (dg < 1.f) dg = 1.f;
  float acc = x[(size_t)n*DD + f] + num[(size_t)n*DD + f]/dg + conv_b[l*DD + f];
  #pragma unroll
  for (int d=0; d<64; ++d)
    acc += hrow[nl][d]*rl[d][f] + hsrow[nl][d]*b2l[d][f];
  x[(size_t)n*DD + f] = acc;
}

// ---------------- head: dense + pooled atomic accumulate ----------------
__global__ void k_dense_pool(const float* x, const float* dW, const float* db,
                             const int* batch, float* pooled){
  __shared__ float wl[64][64];
  __shared__ float xrow[4][64];
  int t = threadIdx.x;
  int f = t & 63, nl = t >> 6;
  for (int idx=t; idx<4096; idx+=256) wl[idx>>6][idx&63] = dW[idx];
  int n = blockIdx.x*4 + nl;
  xrow[nl][f] = x[(size_t)n*DD + f];
  __syncthreads();
  float acc = db[f];
  #pragma unroll
  for (int d=0; d<64; ++d) acc += xrow[nl][d]*wl[d][f];
  atomicAdd(&pooled[(size_t)batch[n]*DD + f], acc);
}

__global__ void k_final(const float* pooled, const int* cnt, const float* oW,
                        const float* ob, float* out){
  __shared__ float p[64];
  int g = blockIdx.x, t = threadIdx.x;
  if (t < 64){
    float c = (float)cnt[g]; if (c < 1.f) c = 1.f;
    p[t] = leaky(pooled[(size_t)g*DD + t] / c);
  }
  __syncthreads();
  float acc = ob[t];
  #pragma unroll
  for (int f=0; f<64; ++f) acc += p[f]*oW[(size_t)f*OUTD + t];
  out[(size_t)g*OUTD + t] = acc;
}

// ws too small -> emit ws_size as diagnostic (deterministic per machine)
__global__ void k_diag(float* out, float val, int n){
  int i = blockIdx.x*256 + threadIdx.x;
  if (i < n) out[i] = (i==0) ? val : 0.f;
}

extern "C" void kernel_launch(void* const* d_in, const int* in_sizes, int n_in,
                              void* d_out, int out_size, void* d_ws, size_t ws_size,
                              hipStream_t stream){
  const float* x_in  = (const float*)d_in[0];
  const int*   ei    = (const int*)d_in[1];
  const float* ea    = (const float*)d_in[2];
  const int*   batch = (const int*)d_in[3];
  const float* ln_s  = (const float*)d_in[4];
  const float* ln_b  = (const float*)d_in[5];
  const float* W1    = (const float*)d_in[6];
  const float* b1    = (const float*)d_in[7];
  const float* W2    = (const float*)d_in[8];
  const float* b2    = (const float*)d_in[9];
  const float* root  = (const float*)d_in[10];
  const float* convb = (const float*)d_in[11];
  const float* dW    = (const float*)d_in[12];
  const float* db    = (const float*)d_in[13];
  const float* oW    = (const float*)d_in[14];
  const float* ob    = (const float*)d_in[15];
  float* out = (float*)d_out;

  char* ws = (char*)d_ws;
  size_t off = 0;
  auto alloc = [&](size_t bytes)->char*{
    char* p = ws + off; off = (off + bytes + 255) & ~(size_t)255; return p;
  };
  float* x_cur  = (float*)alloc((size_t)NN*DD*4);
  float* h      = (float*)alloc((size_t)NN*DD*4);
  float* u      = (float*)alloc((size_t)EE*HH*4);
  float* num    = (float*)alloc((size_t)NN*DD*4);
  float* Hs     = (float*)alloc((size_t)NN*DD*4);
  unsigned short* S   = (unsigned short*)alloc((size_t)4096*8192*2);
  unsigned short* W2T = (unsigned short*)alloc((size_t)8192*64*2);
  int* deg     = (int*)alloc((size_t)NN*4);
  int* row_ptr = (int*)alloc((size_t)(NN+1)*4);
  int* cursor  = (int*)alloc((size_t)NN*4);
  int* edge_id = (int*)alloc((size_t)EE*4);
  int* cnt     = (int*)alloc((size_t)GG*4);
  float* pooled= (float*)alloc((size_t)GG*DD*4);
  size_t needed = off;
  if (ws_size < needed){
    k_diag<<<(out_size+255)/256, 256, 0, stream>>>(out, (float)ws_size, out_size);
    return;
  }

  hipMemsetAsync(deg, 0, (size_t)NN*4, stream);
  hipMemsetAsync(cursor, 0, (size_t)NN*4, stream);
  hipMemsetAsync(cnt, 0, (size_t)GG*4, stream);
  hipMemsetAsync(pooled, 0, (size_t)GG*DD*4, stream);
  hipMemcpyAsync(x_cur, x_in, (size_t)NN*DD*4, hipMemcpyDeviceToDevice, stream);

  k_deg <<<EE/256, 256, 0, stream>>>(ei, deg);
  k_cnt <<<NN/256, 256, 0, stream>>>(batch, cnt);
  k_scan<<<1, 256, 0, stream>>>(deg, row_ptr);
  k_fill<<<EE/256, 256, 0, stream>>>(ei, row_ptr, cursor, edge_id);

  for (int l=0; l<LL; ++l){
    k_ln      <<<NN/4, 256, 0, stream>>>(x_cur, ln_s, ln_b, h, l);
    k_edge_mlp<<<EE/32, 256, 0, stream>>>(ea, W1, b1, u, l);
    k_w2t     <<<(8192*64)/256, 256, 0, stream>>>(W2, W2T, l);
    hipMemsetAsync(num, 0, (size_t)NN*DD*4, stream);
    for (int c=0; c<4; ++c){
      k_sbuild<<<4096, 256, 0, stream>>>(u, h, ei, row_ptr, edge_id, S, Hs, c*4096);
      k_gemm  <<<dim3(32,8), 256, 0, stream>>>(S, W2T, num, c*4096);
    }
    k_update<<<NN/4, 256, 0, stream>>>(x_cur, num, h, Hs, deg, root, b2, convb, l);
  }
  k_dense_pool<<<NN/4, 256, 0, stream>>>(x_cur, dW, db, batch, pooled);
  k_final     <<<GG, 128, 0, stream>>>(pooled, cnt, oW, ob, out);
}

// Round 2
// 1057.295 us; speedup vs baseline: 1.3583x; 1.3583x over previous
//
#include <hip/hip_runtime.h>
#include <hip/hip_bf16.h>

// Problem constants (from reference)
#define NN 16384
#define EE 65536
#define DD 64
#define HH 128
#define LL 3
#define GG 512
#define OUTD 128
#define NEG 0.01f   // jax.nn.leaky_relu default slope

typedef __attribute__((ext_vector_type(8))) short short8;
typedef __attribute__((ext_vector_type(4))) float f32x4;

__device__ __forceinline__ float leaky(float x){ return x > 0.f ? x : NEG * x; }
__device__ __forceinline__ unsigned short f2bf(float f){
  union { float f; unsigned int u; } v; v.f = f;
  unsigned int r = v.u + 0x7fffu + ((v.u >> 16) & 1u);   // RNE
  return (unsigned short)(r >> 16);
}

// ---------------- CSR build ----------------
__global__ void k_deg(const int* ei, int* deg){
  int e = blockIdx.x*256 + threadIdx.x;
  if (e < EE) atomicAdd(&deg[ei[EE + e]], 1);   // row 1 of edge_index = dst
}
__global__ void k_cnt(const int* batch, int* cnt){
  int n = blockIdx.x*256 + threadIdx.x;
  if (n < NN) atomicAdd(&cnt[batch[n]], 1);
}
__global__ void k_scan(const int* deg, int* row_ptr){
  __shared__ int part[256];
  int t = threadIdx.x;
  int base = t*64; int s = 0;
  for (int i=0;i<64;++i) s += deg[base+i];
  part[t] = s; __syncthreads();
  for (int off=1; off<256; off<<=1){
    int v = (t>=off)?part[t-off]:0; __syncthreads();
    part[t] += v; __syncthreads();
  }
  int run = (t==0)?0:part[t-1];
  if (t==0) row_ptr[0] = 0;
  for (int i=0;i<64;++i){ run += deg[base+i]; row_ptr[base+i+1] = run; }
}
__global__ void k_fill(const int* ei, const int* row_ptr, int* cursor, int* edge_id){
  int e = blockIdx.x*256 + threadIdx.x;
  if (e < EE){
    int d = ei[EE + e];
    int pos = row_ptr[d] + atomicAdd(&cursor[d], 1);
    edge_id[pos] = e;
  }
}

// ---------------- LayerNorm + leaky ----------------
__global__ void k_ln(const float* x, const float* scale, const float* bias, float* h, int l){
  int t = threadIdx.x, lane = t & 63, nl = t >> 6;
  int n = blockIdx.x*4 + nl;
  float v = x[(size_t)n*DD + lane];
  float s = v;
  for (int m=1;m<64;m<<=1) s += __shfl_xor(s, m, 64);
  float mu = s * (1.0f/64.0f);
  float dv = v - mu;
  float q = dv*dv;
  for (int m=1;m<64;m<<=1) q += __shfl_xor(q, m, 64);
  float var = q * (1.0f/64.0f);
  float w = dv * rsqrtf(var + 1e-5f) * scale[l*DD + lane] + bias[l*DD + lane];
  h[(size_t)n*DD + lane] = leaky(w);
}

// ---------------- edge MLP: u = leaky(ea @ W1[l] + b1[l])  [E,128] ----------------
// __launch_bounds__(256,2): VGPR cap 256 so w1c[64] stays in registers.
// Round-0 version defaulted to 64 VGPRs -> w1c spilled to scratch -> 470 MB
// phantom FETCH, 183 us/dispatch.
__global__ __launch_bounds__(256, 2)
void k_edge_mlp(const float* ea, const float* W1, const float* b1, float* u, int l){
  __shared__ float eat[32][64];
  int t = threadIdx.x;
  int e0 = blockIdx.x * 32;
  for (int idx = t; idx < 32*64; idx += 256)
    eat[idx>>6][idx&63] = ea[(size_t)(e0 + (idx>>6))*DD + (idx&63)];
  int j = t & 127, half = t >> 7;
  float w1c[64];
  #pragma unroll
  for (int d=0; d<64; ++d) w1c[d] = W1[(size_t)(l*DD + d)*HH + j];
  float bj = b1[l*HH + j];
  __syncthreads();
  for (int i=0;i<16;++i){
    int el = half + 2*i;
    float acc = bj;
    const float4* er = (const float4*)&eat[el][0];
    #pragma unroll
    for (int d4=0; d4<16; ++d4){
      float4 v = er[d4];
      acc += v.x*w1c[4*d4] + v.y*w1c[4*d4+1] + v.z*w1c[4*d4+2] + v.w*w1c[4*d4+3];
    }
    u[(size_t)(e0+el)*HH + j] = leaky(acc);
  }
}

// ---------------- W2[l] -> bf16 transposed [f][kd]  (kd = k*64+d, contiguous K) ----------------
__global__ void k_w2t(const float* W2, unsigned short* W2T, int l){
  int idx = blockIdx.x*256 + threadIdx.x;    // < 64*8192
  int f = idx >> 13, kd = idx & 8191;
  W2T[idx] = f2bf(W2[(size_t)l*HH*DD*DD + (size_t)kd*DD + f]);
}

// ---------------- S-build: S[n_local, kd] = sum_{e->n} u[e,k]*h[src_e,d]  (bf16 out) ----------
__global__ __launch_bounds__(256, 2)
void k_sbuild(const float* u, const float* h, const int* ei,
              const int* row_ptr, const int* edge_id,
              unsigned short* S, float* Hs, int chunk_base){
  __shared__ float eu[32][HH];
  __shared__ float eh[32][DD];
  int t = threadIdx.x;
  int n = chunk_base + blockIdx.x;
  int r0 = row_ptr[n], r1 = row_ptr[n+1];
  float acc[32];
  #pragma unroll
  for (int i=0;i<32;++i) acc[i] = 0.f;
  float hs = 0.f;
  int d = t & 63, k0 = t >> 6;    // thread owns kd = t + 256*i -> d=t&63, k=k0+4i
  for (int rb = r0; rb < r1; rb += 32){
    int nb = min(32, r1 - rb);
    for (int idx = t; idx < nb*HH; idx += 256){
      int el = idx >> 7, c = idx & 127;
      int e = edge_id[rb + el];
      eu[el][c] = u[(size_t)e*HH + c];
    }
    for (int idx = t; idx < nb*DD; idx += 256){
      int el = idx >> 6, c = idx & 63;
      int e = edge_id[rb + el];
      int s = ei[e];               // row 0 of edge_index = src
      eh[el][c] = h[(size_t)s*DD + c];
    }
    __syncthreads();
    for (int el = 0; el < nb; ++el){
      float hv = eh[el][d];
      #pragma unroll
      for (int i=0;i<32;++i) acc[i] += eu[el][k0 + 4*i] * hv;
    }
    if (t < 64){
      for (int el = 0; el < nb; ++el) hs += eh[el][t];
    }
    __syncthreads();
  }
  size_t sb = (size_t)blockIdx.x * 8192;
  #pragma unroll
  for (int i=0;i<32;++i) S[sb + t + 256*i] = f2bf(acc[i]);
  if (t < 64) Hs[(size_t)n*DD + t] = hs;
}

// ---------------- GEMM: num[chunk rows, 64] += S[4096,8192] @ W2T^T, bf16 MFMA, split-K -------
__global__ void k_gemm(const unsigned short* S, const unsigned short* W2T,
                       float* num, int chunk_base){
  __shared__ __align__(16) unsigned short a_lds[128][72];  // +8 pad: conflict-free b128
  __shared__ __align__(16) unsigned short b_lds[64][72];
  int t = threadIdx.x;
  int wave = t >> 6, lane = t & 63;
  int rowblk = blockIdx.x, kseg = blockIdx.y;  // 32 x 8
  int lr = lane & 15, lq = lane >> 4;
  f32x4 acc[2][4];
  for (int a=0;a<2;++a) for (int b=0;b<4;++b) acc[a][b] = (f32x4){0.f,0.f,0.f,0.f};
  int m0 = wave * 32;
  for (int it = 0; it < 16; ++it){            // 16 x 64 = 1024 kd per kseg
    int kbase = kseg*1024 + it*64;
    #pragma unroll
    for (int ii=0; ii<4; ++ii){               // stage A: 128 rows x 64 kd
      int idx = t + 256*ii;
      int r = idx >> 3, c8 = (idx & 7) << 3;
      float4 v = *(const float4*)(S + (size_t)(rowblk*128 + r)*8192 + kbase + c8);
      *(float4*)&a_lds[r][c8] = v;
    }
    #pragma unroll
    for (int ii=0; ii<2; ++ii){               // stage B: 64 f x 64 kd (transposed W2)
      int idx = t + 256*ii;
      int r = idx >> 3, c8 = (idx & 7) << 3;
      float4 v = *(const float4*)(W2T + (size_t)r*8192 + kbase + c8);
      *(float4*)&b_lds[r][c8] = v;
    }
    __syncthreads();
    #pragma unroll
    for (int kk=0; kk<64; kk+=32){
      short8 a0 = *(const short8*)&a_lds[m0 + lr][kk + lq*8];
      short8 a1 = *(const short8*)&a_lds[m0 + 16 + lr][kk + lq*8];
      #pragma unroll
      for (int ft=0; ft<4; ++ft){
        short8 b = *(const short8*)&b_lds[ft*16 + lr][kk + lq*8];
        acc[0][ft] = __builtin_amdgcn_mfma_f32_16x16x32_bf16(a0, b, acc[0][ft], 0, 0, 0);
        acc[1][ft] = __builtin_amdgcn_mfma_f32_16x16x32_bf16(a1, b, acc[1][ft], 0, 0, 0);
      }
    }
    __syncthreads();
  }
  // C/D layout: col = lane&15, row = (lane>>4)*4 + reg   [m89/m91 verified]
  #pragma unroll
  for (int rt=0; rt<2; ++rt)
    #pragma unroll
    for (int ft=0; ft<4; ++ft)
      #pragma unroll
      for (int r=0; r<4; ++r){
        int m = m0 + rt*16 + lq*4 + r;
        int f = ft*16 + lr;
        int n = chunk_base + rowblk*128 + m;
        atomicAdd(&num[(size_t)n*DD + f], acc[rt][ft][r]);
      }
}

// ---------------- node update: x += num/deg + h@root + Hs@b2 + conv_b ----------------
__global__ void k_update(float* x, const float* num, const float* h, const float* Hs,
                         const int* deg, const float* root, const float* b2,
                         const float* conv_b, int l){
  __shared__ float rl[64][64];
  __shared__ float b2l[64][64];
  __shared__ float hrow[4][64];
  __shared__ float hsrow[4][64];
  int t = threadIdx.x;
  int f = t & 63, nl = t >> 6;
  for (int idx=t; idx<4096; idx+=256){
    rl[idx>>6][idx&63]  = root[(size_t)l*4096 + idx];
    b2l[idx>>6][idx&63] = b2[(size_t)l*4096 + idx];
  }
  int n = blockIdx.x*4 + nl;
  hrow[nl][f]  = h[(size_t)n*DD + f];
  hsrow[nl][f] = Hs[(size_t)n*DD + f];
  __syncthreads();
  float dg = (float)deg[n]; if (dg < 1.f) dg = 1.f;
  float acc = x[(size_t)n*DD + f] + num[(size_t)n*DD + f]/dg + conv_b[l*DD + f];
  #pragma unroll
  for (int d=0; d<64; ++d)
    acc += hrow[nl][d]*rl[d][f] + hsrow[nl][d]*b2l[d][f];
  x[(size_t)n*DD + f] = acc;
}

// ---------------- head: dense + pooled atomic accumulate ----------------
__global__ void k_dense_pool(const float* x, const float* dW, const float* db,
                             const int* batch, float* pooled){
  __shared__ float wl[64][64];
  __shared__ float xrow[4][64];
  int t = threadIdx.x;
  int f = t & 63, nl = t >> 6;
  for (int idx=t; idx<4096; idx+=256) wl[idx>>6][idx&63] = dW[idx];
  int n = blockIdx.x*4 + nl;
  xrow[nl][f] = x[(size_t)n*DD + f];
  __syncthreads();
  float acc = db[f];
  #pragma unroll
  for (int d=0; d<64; ++d) acc += xrow[nl][d]*wl[d][f];
  atomicAdd(&pooled[(size_t)batch[n]*DD + f], acc);
}

__global__ void k_final(const float* pooled, const int* cnt, const float* oW,
                        const float* ob, float* out){
  __shared__ float p[64];
  int g = blockIdx.x, t = threadIdx.x;
  if (t < 64){
    float c = (float)cnt[g]; if (c < 1.f) c = 1.f;
    p[t] = leaky(pooled[(size_t)g*DD + t] / c);
  }
  __syncthreads();
  float acc = ob[t];
  #pragma unroll
  for (int f=0; f<64; ++f) acc += p[f]*oW[(size_t)f*OUTD + t];
  out[(size_t)g*OUTD + t] = acc;
}

// ws too small -> emit ws_size as diagnostic (deterministic per machine)
__global__ void k_diag(float* out, float val, int n){
  int i = blockIdx.x*256 + threadIdx.x;
  if (i < n) out[i] = (i==0) ? val : 0.f;
}

extern "C" void kernel_launch(void* const* d_in, const int* in_sizes, int n_in,
                              void* d_out, int out_size, void* d_ws, size_t ws_size,
                              hipStream_t stream){
  const float* x_in  = (const float*)d_in[0];
  const int*   ei    = (const int*)d_in[1];
  const float* ea    = (const float*)d_in[2];
  const int*   batch = (const int*)d_in[3];
  const float* ln_s  = (const float*)d_in[4];
  const float* ln_b  = (const float*)d_in[5];
  const float* W1    = (const float*)d_in[6];
  const float* b1    = (const float*)d_in[7];
  const float* W2    = (const float*)d_in[8];
  const float* b2    = (const float*)d_in[9];
  const float* root  = (const float*)d_in[10];
  const float* convb = (const float*)d_in[11];
  const float* dW    = (const float*)d_in[12];
  const float* db    = (const float*)d_in[13];
  const float* oW    = (const float*)d_in[14];
  const float* ob    = (const float*)d_in[15];
  float* out = (float*)d_out;

  char* ws = (char*)d_ws;
  size_t off = 0;
  auto alloc = [&](size_t bytes)->char*{
    char* p = ws + off; off = (off + bytes + 255) & ~(size_t)255; return p;
  };
  float* x_cur  = (float*)alloc((size_t)NN*DD*4);
  float* h      = (float*)alloc((size_t)NN*DD*4);
  float* u      = (float*)alloc((size_t)EE*HH*4);
  float* num    = (float*)alloc((size_t)NN*DD*4);
  float* Hs     = (float*)alloc((size_t)NN*DD*4);
  unsigned short* S   = (unsigned short*)alloc((size_t)4096*8192*2);
  unsigned short* W2T = (unsigned short*)alloc((size_t)8192*64*2);
  int* deg     = (int*)alloc((size_t)NN*4);
  int* row_ptr = (int*)alloc((size_t)(NN+1)*4);
  int* cursor  = (int*)alloc((size_t)NN*4);
  int* edge_id = (int*)alloc((size_t)EE*4);
  int* cnt     = (int*)alloc((size_t)GG*4);
  float* pooled= (float*)alloc((size_t)GG*DD*4);
  size_t needed = off;
  if (ws_size < needed){
    k_diag<<<(out_size+255)/256, 256, 0, stream>>>(out, (float)ws_size, out_size);
    return;
  }

  hipMemsetAsync(deg, 0, (size_t)NN*4, stream);
  hipMemsetAsync(cursor, 0, (size_t)NN*4, stream);
  hipMemsetAsync(cnt, 0, (size_t)GG*4, stream);
  hipMemsetAsync(pooled, 0, (size_t)GG*DD*4, stream);
  hipMemcpyAsync(x_cur, x_in, (size_t)NN*DD*4, hipMemcpyDeviceToDevice, stream);

  k_deg <<<EE/256, 256, 0, stream>>>(ei, deg);
  k_cnt <<<NN/256, 256, 0, stream>>>(batch, cnt);
  k_scan<<<1, 256, 0, stream>>>(deg, row_ptr);
  k_fill<<<EE/256, 256, 0, stream>>>(ei, row_ptr, cursor, edge_id);

  for (int l=0; l<LL; ++l){
    k_ln      <<<NN/4, 256, 0, stream>>>(x_cur, ln_s, ln_b, h, l);
    k_edge_mlp<<<EE/32, 256, 0, stream>>>(ea, W1, b1, u, l);
    k_w2t     <<<(8192*64)/256, 256, 0, stream>>>(W2, W2T, l);
    hipMemsetAsync(num, 0, (size_t)NN*DD*4, stream);
    for (int c=0; c<4; ++c){
      k_sbuild<<<4096, 256, 0, stream>>>(u, h, ei, row_ptr, edge_id, S, Hs, c*4096);
      k_gemm  <<<dim3(32,8), 256, 0, stream>>>(S, W2T, num, c*4096);
    }
    k_update<<<NN/4, 256, 0, stream>>>(x_cur, num, h, Hs, deg, root, b2, convb, l);
  }
  k_dense_pool<<<NN/4, 256, 0, stream>>>(x_cur, dW, db, batch, pooled);
  k_final     <<<GG, 128, 0, stream>>>(pooled, cnt, oW, ob, out);
}

// Round 4
// 1024.740 us; speedup vs baseline: 1.4014x; 1.0318x over previous
//
#include <hip/hip_runtime.h>
#include <hip/hip_bf16.h>

// Problem constants (from reference)
#define NN 16384
#define EE 65536
#define DD 64
#define HH 128
#define LL 3
#define GG 512
#define OUTD 128
#define NEG 0.01f   // jax.nn.leaky_relu default slope

typedef __attribute__((ext_vector_type(8))) short short8;
typedef __attribute__((ext_vector_type(4))) float f32x4;

__device__ __forceinline__ float leaky(float x){ return x > 0.f ? x : NEG * x; }
__device__ __forceinline__ unsigned short f2bf(float f){
  union { float f; unsigned int u; } v; v.f = f;
  unsigned int r = v.u + 0x7fffu + ((v.u >> 16) & 1u);   // RNE
  return (unsigned short)(r >> 16);
}

// ---------------- CSR build ----------------
__global__ void k_deg(const int* ei, int* deg){
  int e = blockIdx.x*256 + threadIdx.x;
  if (e < EE) atomicAdd(&deg[ei[EE + e]], 1);   // row 1 of edge_index = dst
}
__global__ void k_cnt(const int* batch, int* cnt){
  int n = blockIdx.x*256 + threadIdx.x;
  if (n < NN) atomicAdd(&cnt[batch[n]], 1);
}
__global__ void k_scan(const int* deg, int* row_ptr){
  __shared__ int part[256];
  int t = threadIdx.x;
  int base = t*64; int s = 0;
  for (int i=0;i<64;++i) s += deg[base+i];
  part[t] = s; __syncthreads();
  for (int off=1; off<256; off<<=1){
    int v = (t>=off)?part[t-off]:0; __syncthreads();
    part[t] += v; __syncthreads();
  }
  int run = (t==0)?0:part[t-1];
  if (t==0) row_ptr[0] = 0;
  for (int i=0;i<64;++i){ run += deg[base+i]; row_ptr[base+i+1] = run; }
}
__global__ void k_fill(const int* ei, const int* row_ptr, int* cursor,
                       int* edge_id, int* src_sorted){
  int e = blockIdx.x*256 + threadIdx.x;
  if (e < EE){
    int d = ei[EE + e];
    int pos = row_ptr[d] + atomicAdd(&cursor[d], 1);
    edge_id[pos] = e;
    src_sorted[pos] = ei[e];      // row 0 of edge_index = src
  }
}

// ---------------- one-time bf16 prep: ea and W1^T ----------------
__global__ void k_prep_ea(const float* ea, unsigned short* eab){
  int i = blockIdx.x*256 + threadIdx.x;   // EE*DD
  eab[i] = f2bf(ea[i]);
}
__global__ void k_prep_w1t(const float* W1, unsigned short* W1T){
  int i = blockIdx.x*256 + threadIdx.x;   // LL*HH*DD
  int l = i >> 13, r = i & 8191;
  int j = r >> 6, d = r & 63;
  W1T[i] = f2bf(W1[(size_t)l*DD*HH + d*HH + j]);   // W1T[l][j][d]
}

// ---------------- LayerNorm + leaky ----------------
__global__ void k_ln(const float* x, const float* scale, const float* bias, float* h, int l){
  int t = threadIdx.x, lane = t & 63, nl = t >> 6;
  int n = blockIdx.x*4 + nl;
  float v = x[(size_t)n*DD + lane];
  float s = v;
  for (int m=1;m<64;m<<=1) s += __shfl_xor(s, m, 64);
  float mu = s * (1.0f/64.0f);
  float dv = v - mu;
  float q = dv*dv;
  for (int m=1;m<64;m<<=1) q += __shfl_xor(q, m, 64);
  float var = q * (1.0f/64.0f);
  float w = dv * rsqrtf(var + 1e-5f) * scale[l*DD + lane] + bias[l*DD + lane];
  h[(size_t)n*DD + lane] = leaky(w);
}

// ---------------- edge MLP via MFMA: ug = bf16(leaky(ea @ W1[l] + b1[l]))  [E,128] ----------
// Tile: 128 edges x 128 j per block; 4 waves = 2x2 wave-grid of 64x64.
__global__ __launch_bounds__(256, 2)
void k_edge_mlp(const unsigned short* eab, const unsigned short* W1T, const float* b1,
                unsigned short* ug, int l){
  __shared__ __align__(16) unsigned short a_lds[128][72];   // ea tile  [e][d]
  __shared__ __align__(16) unsigned short b_lds[128][72];   // W1T      [j][d]
  __shared__ __align__(16) unsigned short c_lds[128][136];  // out      [e][j]
  int t = threadIdx.x;
  int e0 = blockIdx.x * 128;
  {
    int row = t >> 1, col = (t & 1) * 32;
    const float4* sa = (const float4*)(eab + (size_t)(e0 + row)*DD + col);
    const float4* sb = (const float4*)(W1T + (size_t)l*HH*DD + (size_t)row*DD + col);
    #pragma unroll
    for (int i=0;i<4;++i){
      *(float4*)&a_lds[row][col + 8*i] = sa[i];
      *(float4*)&b_lds[row][col + 8*i] = sb[i];
    }
  }
  __syncthreads();
  int wave = t >> 6, lane = t & 63;
  int m0 = (wave >> 1) * 64, j0 = (wave & 1) * 64;
  int lr = lane & 15, lq = lane >> 4;
  f32x4 acc[4][4];
  #pragma unroll
  for (int a=0;a<4;++a)
    #pragma unroll
    for (int b=0;b<4;++b) acc[a][b] = (f32x4){0.f,0.f,0.f,0.f};
  #pragma unroll
  for (int ks=0; ks<2; ++ks){
    short8 av[4];
    #pragma unroll
    for (int mt=0; mt<4; ++mt) av[mt] = *(const short8*)&a_lds[m0 + mt*16 + lr][ks*32 + lq*8];
    #pragma unroll
    for (int jt=0; jt<4; ++jt){
      short8 bv = *(const short8*)&b_lds[j0 + jt*16 + lr][ks*32 + lq*8];
      #pragma unroll
      for (int mt=0; mt<4; ++mt)
        acc[mt][jt] = __builtin_amdgcn_mfma_f32_16x16x32_bf16(av[mt], bv, acc[mt][jt], 0, 0, 0);
    }
  }
  // C/D: col = lane&15, row = (lane>>4)*4 + r
  #pragma unroll
  for (int mt=0; mt<4; ++mt)
    #pragma unroll
    for (int jt=0; jt<4; ++jt){
      int col = j0 + jt*16 + lr;
      float bj = b1[l*HH + col];
      #pragma unroll
      for (int r=0; r<4; ++r){
        int row = m0 + mt*16 + lq*4 + r;
        c_lds[row][col] = f2bf(leaky(acc[mt][jt][r] + bj));
      }
    }
  __syncthreads();
  {
    int row = t >> 1, half = t & 1;
    float4* dst = (float4*)(ug + (size_t)(e0 + row)*HH + half*64);
    #pragma unroll
    for (int i=0;i<8;++i) dst[i] = *(const float4*)&c_lds[row][half*64 + 8*i];
  }
}

// ---------------- W2[l] -> bf16 transposed [f][kd]  (kd = k*64+d, contiguous K) ----------------
__global__ void k_w2t(const float* W2, unsigned short* W2T, int l){
  int idx = blockIdx.x*256 + threadIdx.x;    // < 64*8192
  int f = idx >> 13, kd = idx & 8191;
  W2T[idx] = f2bf(W2[(size_t)l*HH*DD*DD + (size_t)kd*DD + f]);
}

// ---------------- S-build v2: register-resident outer-product ----------------
// One wave per node. Lane owns k = {2*lane, 2*lane+1} (via u dword) and all 64 d
// in acc registers. h broadcast via v_readlane. No LDS, no barriers.
// S[nloc][k*64+d] = sum_e u[e,k]*h[src_e,d]; Hs[n][d] = sum_e h[src_e,d].
// ROUND-3 BUG FIXED HERE: pack buffer was 32 bf16 (half a d-row) -> d=32..63
// stayed 0xAA poison. Now 64 bf16 = full row (128 B) per k.
__global__ __launch_bounds__(256, 2)
void k_sbuild2(const unsigned short* ug, const float* h, const int* row_ptr,
               const int* edge_id, const int* src_sorted,
               unsigned short* S, float* Hs, int chunk_base){
  int t = threadIdx.x, wave = t >> 6, lane = t & 63;
  int nloc = blockIdx.x*4 + wave;
  int n = chunk_base + nloc;
  int r0 = row_ptr[n], r1 = row_ptr[n+1];
  float acc0[64], acc1[64];
  #pragma unroll
  for (int d=0; d<64; ++d){ acc0[d] = 0.f; acc1[d] = 0.f; }
  float hs = 0.f;
  for (int pos = r0; pos < r1; ++pos){
    int e = edge_id[pos];
    int s = src_sorted[pos];
    float hv = h[(size_t)s*DD + lane];
    unsigned int up = *(const unsigned int*)(ug + (size_t)e*HH + 2*lane);
    float u0 = __uint_as_float(up << 16);
    float u1 = __uint_as_float(up & 0xFFFF0000u);
    hs += hv;
    int hvi = __float_as_int(hv);
    #pragma unroll
    for (int d=0; d<64; ++d){
      float sh = __int_as_float(__builtin_amdgcn_readlane(hvi, d));
      acc0[d] += u0 * sh;
      acc1[d] += u1 * sh;
    }
  }
  unsigned short* Srow = S + (size_t)nloc*8192;
  #pragma unroll
  for (int k2=0; k2<2; ++k2){
    union { unsigned int u[32]; float4 v[8]; } buf;
    #pragma unroll
    for (int i=0;i<32;++i){
      float a0 = k2 ? acc1[2*i]   : acc0[2*i];
      float a1 = k2 ? acc1[2*i+1] : acc0[2*i+1];
      buf.u[i] = (unsigned int)f2bf(a0) | ((unsigned int)f2bf(a1) << 16);
    }
    float4* dst = (float4*)(Srow + (size_t)(2*lane + k2)*64);
    #pragma unroll
    for (int i=0;i<8;++i) dst[i] = buf.v[i];
  }
  Hs[(size_t)n*DD + lane] = hs;
}

// ---------------- GEMM: num[chunk rows, 64] += S[4096,8192] @ W2T^T, bf16 MFMA, split-K -------
__global__ void k_gemm(const unsigned short* S, const unsigned short* W2T,
                       float* num, int chunk_base){
  __shared__ __align__(16) unsigned short a_lds[128][72];  // +8 pad: conflict-free b128
  __shared__ __align__(16) unsigned short b_lds[64][72];
  int t = threadIdx.x;
  int wave = t >> 6, lane = t & 63;
  int rowblk = blockIdx.x, kseg = blockIdx.y;  // 32 x 8
  int lr = lane & 15, lq = lane >> 4;
  f32x4 acc[2][4];
  for (int a=0;a<2;++a) for (int b=0;b<4;++b) acc[a][b] = (f32x4){0.f,0.f,0.f,0.f};
  int m0 = wave * 32;
  for (int it = 0; it < 16; ++it){            // 16 x 64 = 1024 kd per kseg
    int kbase = kseg*1024 + it*64;
    #pragma unroll
    for (int ii=0; ii<4; ++ii){               // stage A: 128 rows x 64 kd
      int idx = t + 256*ii;
      int r = idx >> 3, c8 = (idx & 7) << 3;
      float4 v = *(const float4*)(S + (size_t)(rowblk*128 + r)*8192 + kbase + c8);
      *(float4*)&a_lds[r][c8] = v;
    }
    #pragma unroll
    for (int ii=0; ii<2; ++ii){               // stage B: 64 f x 64 kd (transposed W2)
      int idx = t + 256*ii;
      int r = idx >> 3, c8 = (idx & 7) << 3;
      float4 v = *(const float4*)(W2T + (size_t)r*8192 + kbase + c8);
      *(float4*)&b_lds[r][c8] = v;
    }
    __syncthreads();
    #pragma unroll
    for (int kk=0; kk<64; kk+=32){
      short8 a0 = *(const short8*)&a_lds[m0 + lr][kk + lq*8];
      short8 a1 = *(const short8*)&a_lds[m0 + 16 + lr][kk + lq*8];
      #pragma unroll
      for (int ft=0; ft<4; ++ft){
        short8 b = *(const short8*)&b_lds[ft*16 + lr][kk + lq*8];
        acc[0][ft] = __builtin_amdgcn_mfma_f32_16x16x32_bf16(a0, b, acc[0][ft], 0, 0, 0);
        acc[1][ft] = __builtin_amdgcn_mfma_f32_16x16x32_bf16(a1, b, acc[1][ft], 0, 0, 0);
      }
    }
    __syncthreads();
  }
  // C/D layout: col = lane&15, row = (lane>>4)*4 + reg   [m89/m91 verified]
  #pragma unroll
  for (int rt=0; rt<2; ++rt)
    #pragma unroll
    for (int ft=0; ft<4; ++ft)
      #pragma unroll
      for (int r=0; r<4; ++r){
        int m = m0 + rt*16 + lq*4 + r;
        int f = ft*16 + lr;
        int n = chunk_base + rowblk*128 + m;
        atomicAdd(&num[(size_t)n*DD + f], acc[rt][ft][r]);
      }
}

// ---------------- node update: x += num/deg + h@root + Hs@b2 + conv_b ----------------
__global__ void k_update(float* x, const float* num, const float* h, const float* Hs,
                         const int* deg, const float* root, const float* b2,
                         const float* conv_b, int l){
  __shared__ float rl[64][64];
  __shared__ float b2l[64][64];
  __shared__ float hrow[4][64];
  __shared__ float hsrow[4][64];
  int t = threadIdx.x;
  int f = t & 63, nl = t >> 6;
  for (int idx=t; idx<4096; idx+=256){
    rl[idx>>6][idx&63]  = root[(size_t)l*4096 + idx];
    b2l[idx>>6][idx&63] = b2[(size_t)l*4096 + idx];
  }
  int n = blockIdx.x*4 + nl;
  hrow[nl][f]  = h[(size_t)n*DD + f];
  hsrow[nl][f] = Hs[(size_t)n*DD + f];
  __syncthreads();
  float dg = (float)deg[n]; if (dg < 1.f) dg = 1.f;
  float acc = x[(size_t)n*DD + f] + num[(size_t)n*DD + f]/dg + conv_b[l*DD + f];
  #pragma unroll
  for (int d=0; d<64; ++d)
    acc += hrow[nl][d]*rl[d][f] + hsrow[nl][d]*b2l[d][f];
  x[(size_t)n*DD + f] = acc;
}

// ---------------- head: dense + pooled atomic accumulate ----------------
__global__ void k_dense_pool(const float* x, const float* dW, const float* db,
                             const int* batch, float* pooled){
  __shared__ float wl[64][64];
  __shared__ float xrow[4][64];
  int t = threadIdx.x;
  int f = t & 63, nl = t >> 6;
  for (int idx=t; idx<4096; idx+=256) wl[idx>>6][idx&63] = dW[idx];
  int n = blockIdx.x*4 + nl;
  xrow[nl][f] = x[(size_t)n*DD + f];
  __syncthreads();
  float acc = db[f];
  #pragma unroll
  for (int d=0; d<64; ++d) acc += xrow[nl][d]*wl[d][f];
  atomicAdd(&pooled[(size_t)batch[n]*DD + f], acc);
}

__global__ void k_final(const float* pooled, const int* cnt, const float* oW,
                        const float* ob, float* out){
  __shared__ float p[64];
  int g = blockIdx.x, t = threadIdx.x;
  if (t < 64){
    float c = (float)cnt[g]; if (c < 1.f) c = 1.f;
    p[t] = leaky(pooled[(size_t)g*DD + t] / c);
  }
  __syncthreads();
  float acc = ob[t];
  #pragma unroll
  for (int f=0; f<64; ++f) acc += p[f]*oW[(size_t)f*OUTD + t];
  out[(size_t)g*OUTD + t] = acc;
}

// ws too small -> emit ws_size as diagnostic (deterministic per machine)
__global__ void k_diag(float* out, float val, int n){
  int i = blockIdx.x*256 + threadIdx.x;
  if (i < n) out[i] = (i==0) ? val : 0.f;
}

extern "C" void kernel_launch(void* const* d_in, const int* in_sizes, int n_in,
                              void* d_out, int out_size, void* d_ws, size_t ws_size,
                              hipStream_t stream){
  const float* x_in  = (const float*)d_in[0];
  const int*   ei    = (const int*)d_in[1];
  const float* ea    = (const float*)d_in[2];
  const int*   batch = (const int*)d_in[3];
  const float* ln_s  = (const float*)d_in[4];
  const float* ln_b  = (const float*)d_in[5];
  const float* W1    = (const float*)d_in[6];
  const float* b1    = (const float*)d_in[7];
  const float* W2    = (const float*)d_in[8];
  const float* b2    = (const float*)d_in[9];
  const float* root  = (const float*)d_in[10];
  const float* convb = (const float*)d_in[11];
  const float* dW    = (const float*)d_in[12];
  const float* db    = (const float*)d_in[13];
  const float* oW    = (const float*)d_in[14];
  const float* ob    = (const float*)d_in[15];
  float* out = (float*)d_out;

  char* ws = (char*)d_ws;
  size_t off = 0;
  auto alloc = [&](size_t bytes)->char*{
    char* p = ws + off; off = (off + bytes + 255) & ~(size_t)255; return p;
  };
  float* x_cur  = (float*)alloc((size_t)NN*DD*4);
  float* h      = (float*)alloc((size_t)NN*DD*4);
  unsigned short* ug  = (unsigned short*)alloc((size_t)EE*HH*2);
  float* num    = (float*)alloc((size_t)NN*DD*4);
  float* Hs     = (float*)alloc((size_t)NN*DD*4);
  unsigned short* S   = (unsigned short*)alloc((size_t)4096*8192*2);
  unsigned short* W2T = (unsigned short*)alloc((size_t)8192*64*2);
  unsigned short* eab = (unsigned short*)alloc((size_t)EE*DD*2);
  unsigned short* W1T = (unsigned short*)alloc((size_t)LL*HH*DD*2);
  int* deg     = (int*)alloc((size_t)NN*4);
  int* row_ptr = (int*)alloc((size_t)(NN+1)*4);
  int* cursor  = (int*)alloc((size_t)NN*4);
  int* edge_id = (int*)alloc((size_t)EE*4);
  int* src_sorted = (int*)alloc((size_t)EE*4);
  int* cnt     = (int*)alloc((size_t)GG*4);
  float* pooled= (float*)alloc((size_t)GG*DD*4);
  size_t needed = off;
  if (ws_size < needed){
    k_diag<<<(out_size+255)/256, 256, 0, stream>>>(out, (float)ws_size, out_size);
    return;
  }

  hipMemsetAsync(deg, 0, (size_t)NN*4, stream);
  hipMemsetAsync(cursor, 0, (size_t)NN*4, stream);
  hipMemsetAsync(cnt, 0, (size_t)GG*4, stream);
  hipMemsetAsync(pooled, 0, (size_t)GG*DD*4, stream);
  hipMemcpyAsync(x_cur, x_in, (size_t)NN*DD*4, hipMemcpyDeviceToDevice, stream);

  k_deg <<<EE/256, 256, 0, stream>>>(ei, deg);
  k_cnt <<<NN/256, 256, 0, stream>>>(batch, cnt);
  k_scan<<<1, 256, 0, stream>>>(deg, row_ptr);
  k_fill<<<EE/256, 256, 0, stream>>>(ei, row_ptr, cursor, edge_id, src_sorted);
  k_prep_ea <<<(EE*DD)/256, 256, 0, stream>>>(ea, eab);
  k_prep_w1t<<<(LL*HH*DD)/256, 256, 0, stream>>>(W1, W1T);

  for (int l=0; l<LL; ++l){
    k_ln      <<<NN/4, 256, 0, stream>>>(x_cur, ln_s, ln_b, h, l);
    k_edge_mlp<<<EE/128, 256, 0, stream>>>(eab, W1T, b1, ug, l);
    k_w2t     <<<(8192*64)/256, 256, 0, stream>>>(W2, W2T, l);
    hipMemsetAsync(num, 0, (size_t)NN*DD*4, stream);
    for (int c=0; c<4; ++c){
      k_sbuild2<<<1024, 256, 0, stream>>>(ug, h, row_ptr, edge_id, src_sorted, S, Hs, c*4096);
      k_gemm   <<<dim3(32,8), 256, 0, stream>>>(S, W2T, num, c*4096);
    }
    k_update<<<NN/4, 256, 0, stream>>>(x_cur, num, h, Hs, deg, root, b2, convb, l);
  }
  k_dense_pool<<<NN/4, 256, 0, stream>>>(x_cur, dW, db, batch, pooled);
  k_final     <<<GG, 128, 0, stream>>>(pooled, cnt, oW, ob, out);
}